// Round 8
// baseline (674.156 us; speedup 1.0000x reference)
//
#include <hip/hip_runtime.h>
#include <math.h>

#define NN 50000
#define NP 50048   // padded rows (multiple of 64)
#define NE 600000
#define NG 1024
#define NL 5
#define NT (NP / 64)     // 782 M-tiles
#define GRUGRID 256      // persistent blocks (1 per CU)
// Hd = 128, Fin = 74, C = 2

typedef __attribute__((ext_vector_type(8))) short bfrag8;
typedef __attribute__((ext_vector_type(4))) float f32x4;

// ---- fast transcendentals (v_exp_f32 / v_rcp_f32; abs err ~1e-6, budget is 1.4e-2) ----
__device__ __forceinline__ float fexp_(float x) { return __builtin_amdgcn_exp2f(x * 1.44269504f); }
__device__ __forceinline__ float sig_(float x)  { return __builtin_amdgcn_rcpf(1.f + fexp_(-x)); }
__device__ __forceinline__ float ftanh_(float x){ return fmaf(2.f, __builtin_amdgcn_rcpf(1.f + fexp_(-2.f * x)), -1.f); }
__device__ __forceinline__ float fexpm1_(float x){ return fexp_(x) - 1.f; }

__device__ __forceinline__ unsigned short bf16r_(float x) {
  union { float f; unsigned u; } v; v.f = x;
  unsigned u = v.u;
  return (unsigned short)((u + 0x7FFFu + ((u >> 16) & 1u)) >> 16);
}
__device__ __forceinline__ float bf16tof_(unsigned short h) {
  union { float f; unsigned u; } v; v.u = ((unsigned)h) << 16;
  return v.f;
}

// async global->LDS, 16B per lane; lds dst = uniform base + lane*16
__device__ __forceinline__ void gl_lds16(const unsigned short* g, unsigned short* l) {
  __builtin_amdgcn_global_load_lds(
      (const __attribute__((address_space(1))) unsigned int*)g,
      (__attribute__((address_space(3))) unsigned int*)l, 16, 0, 0);
}

// ---------------- input projection: h = feats @ W_in + b_in ----------------
__global__ __launch_bounds__(256) void k_input_proj(
    const float* __restrict__ feats, const float* __restrict__ W_in,
    const float* __restrict__ b_in, float* __restrict__ h)
{
  const int j = threadIdx.x & 127;
  const int half = threadIdx.x >> 7;   // wave-uniform
  float wcol[74];
#pragma unroll
  for (int k = 0; k < 74; ++k) wcol[k] = W_in[k * 128 + j];
  const float bj = b_in[j];
  for (int p = blockIdx.x; p < NN / 2; p += gridDim.x) {
    int node = __builtin_amdgcn_readfirstlane(p * 2 + half);
    const float* fr = feats + (size_t)node * 74;
    float acc = bj;
#pragma unroll
    for (int k = 0; k < 74; ++k) acc = fmaf(fr[k], wcol[k], acc);
    h[(size_t)node * 128 + j] = acc;
  }
}

// ---------------- per-layer BN scale/shift precompute (all layers at once) ----------------
__global__ void k_bnprep_all(const float* __restrict__ g, const float* __restrict__ b,
                             const float* __restrict__ m, const float* __restrict__ v,
                             float* __restrict__ bnp)
{
  int l = blockIdx.x;
  int j = threadIdx.x;
  float s = g[l * 128 + j] * rsqrtf(v[l * 128 + j] + 1e-5f);
  bnp[l * 256 + j] = s;
  bnp[l * 256 + 128 + j] = b[l * 128 + j] - m[l * 128 + j] * s;
}

// ---------------- GRU weight prepack ----------------
__global__ __launch_bounds__(256) void k_wpack(
    const float* __restrict__ w_ih, const float* __restrict__ w_hh,
    const float* __restrict__ b_ih, const float* __restrict__ b_hh,
    unsigned short* __restrict__ Wp, float* __restrict__ bcat)
{
  int idx = blockIdx.x * 256 + threadIdx.x;
  int n = idx >> 8, k = idx & 255;
  float val;
  if (n < 256) {
    val = (k < 128) ? fmaf(1.00001f, w_ih[n * 256 + k], w_hh[n * 128 + k])
                    : w_ih[n * 256 + k];
  } else if (n < 384) {
    val = (k < 128) ? 1.00001f * w_ih[n * 256 + k] : w_ih[n * 256 + k];
  } else {
    int g = n - 128;
    val = (k < 128) ? w_hh[g * 128 + k] : 0.f;
  }
  Wp[(size_t)(k >> 5) * 16384 + n * 32 + (k & 31)] = bf16r_(val);
  if (k == 0) {
    float bc;
    if (n < 256) bc = b_ih[n] + b_hh[n];
    else if (n < 384) bc = b_ih[n];
    else bc = b_hh[n - 128];
    bcat[n] = bc;
  }
}

// ---------------- LSTM weight prepack ----------------
__global__ __launch_bounds__(256) void k_wpack_lstm(
    const float* __restrict__ lwih_f, const float* __restrict__ lwih_b,
    const float* __restrict__ lwhh_b,
    const float* __restrict__ lbih_f, const float* __restrict__ lbhh_f,
    const float* __restrict__ lbih_b, const float* __restrict__ lbhh_b,
    unsigned short* __restrict__ Wihf, unsigned short* __restrict__ Wihb,
    unsigned short* __restrict__ Whhb, float* __restrict__ bcf, float* __restrict__ bcb)
{
  int idx = blockIdx.x * 256 + threadIdx.x;
  if (idx < 131072) {
    int n = idx >> 8, k = idx & 255;
    Wihf[(size_t)(k >> 5) * 16384 + n * 32 + (k & 31)] = bf16r_(lwih_f[n * 256 + k]);
  } else if (idx < 262144) {
    int i2 = idx - 131072; int n = i2 >> 8, k = i2 & 255;
    Wihb[(size_t)(k >> 5) * 16384 + n * 32 + (k & 31)] = bf16r_(lwih_b[n * 256 + k]);
  } else if (idx < 327680) {
    int i2 = idx - 262144; int n = i2 >> 7, k = i2 & 127;
    Whhb[(size_t)(k >> 5) * 16384 + n * 32 + (k & 31)] = bf16r_(lwhh_b[n * 128 + k]);
  }
  if (idx < 512) {
    bcf[idx] = lbih_f[idx] + lbhh_f[idx];
    bcb[idx] = lbih_b[idx] + lbhh_b[idx];
  }
}

// ---------------- prep: x = BN(h) -> swizzled bf16 plane; + wnode ----------------
__global__ __launch_bounds__(256) void k_prep(
    const float* __restrict__ h, const float* __restrict__ bnp,
    const float* __restrict__ w_aw, const float* __restrict__ b_aw,
    unsigned short* __restrict__ xhi, float* __restrict__ wnode)
{
  int t = blockIdx.x * 256 + threadIdx.x;
  int row = t >> 4, c = t & 15;
  const float* hp = h + (size_t)row * 128 + c * 8;
  float4 h0 = *(const float4*)(hp);
  float4 h1 = *(const float4*)(hp + 4);
  float4 s0 = *(const float4*)(bnp + c * 8);
  float4 s1 = *(const float4*)(bnp + c * 8 + 4);
  float4 t0 = *(const float4*)(bnp + 128 + c * 8);
  float4 t1 = *(const float4*)(bnp + 128 + c * 8 + 4);
  float x[8] = { fmaf(h0.x, s0.x, t0.x), fmaf(h0.y, s0.y, t0.y),
                 fmaf(h0.z, s0.z, t0.z), fmaf(h0.w, s0.w, t0.w),
                 fmaf(h1.x, s1.x, t1.x), fmaf(h1.y, s1.y, t1.y),
                 fmaf(h1.z, s1.z, t1.z), fmaf(h1.w, s1.w, t1.w) };
  unsigned hiw[4];
#pragma unroll
  for (int i = 0; i < 4; ++i) {
    unsigned short ha = bf16r_(x[2 * i]), hb = bf16r_(x[2 * i + 1]);
    hiw[i] = (unsigned)ha | ((unsigned)hb << 16);
  }
  size_t dst = (size_t)row * 16 + (c ^ (row & 7));
  ((uint4*)xhi)[dst] = make_uint4(hiw[0], hiw[1], hiw[2], hiw[3]);
  const float4 wa0 = *(const float4*)(w_aw + c * 8);
  const float4 wa1 = *(const float4*)(w_aw + c * 8 + 4);
  float p = h0.x * wa0.x + h0.y * wa0.y + h0.z * wa0.z + h0.w * wa0.w +
            h1.x * wa1.x + h1.y * wa1.y + h1.z * wa1.z + h1.w * wa1.w;
#pragma unroll
  for (int o = 8; o > 0; o >>= 1) p += __shfl_xor(p, o);
  if (c == 0) wnode[row] = sig_(p + b_aw[0]);
}

// ---------------- CSR build ----------------
__global__ __launch_bounds__(256) void k_hist(const int* __restrict__ dst, int* __restrict__ deg)
{
  int t = blockIdx.x * 256 + threadIdx.x;
  if (t < NE) atomicAdd(&deg[dst[t]], 1);
}

__global__ __launch_bounds__(256) void k_scan1(const int* __restrict__ deg, int* __restrict__ bsum)
{
  __shared__ int red[4];
  int i = blockIdx.x * 256 + threadIdx.x;
  int d = (i < NN) ? deg[i] : 0;
  int s = d;
#pragma unroll
  for (int o = 32; o > 0; o >>= 1) s += __shfl_xor(s, o);
  if ((threadIdx.x & 63) == 0) red[threadIdx.x >> 6] = s;
  __syncthreads();
  if (threadIdx.x == 0) bsum[blockIdx.x] = red[0] + red[1] + red[2] + red[3];
}

__global__ __launch_bounds__(256) void k_scan2(const int* __restrict__ bsum, int* __restrict__ boff,
                                               int* __restrict__ rowptr)
{
  __shared__ int part[256];
  int t = threadIdx.x;
  int v = (t < 196) ? bsum[t] : 0;
  part[t] = v;
  __syncthreads();
  for (int o = 1; o < 256; o <<= 1) {
    int u = (t >= o) ? part[t - o] : 0;
    __syncthreads();
    part[t] += u;
    __syncthreads();
  }
  if (t < 196) boff[t] = part[t] - v;
  if (t == 0) rowptr[NN] = NE;
}

__global__ __launch_bounds__(256) void k_scan3(const int* __restrict__ deg, const int* __restrict__ boff,
                                               int* __restrict__ rowptr)
{
  __shared__ int part[256];
  int t = threadIdx.x;
  int i = blockIdx.x * 256 + t;
  int d = (i < NN) ? deg[i] : 0;
  part[t] = d;
  __syncthreads();
  for (int o = 1; o < 256; o <<= 1) {
    int u = (t >= o) ? part[t - o] : 0;
    __syncthreads();
    part[t] += u;
    __syncthreads();
  }
  if (i < NN) rowptr[i] = boff[blockIdx.x] + part[t] - d;
}

__global__ __launch_bounds__(256) void k_fill(
    const int* __restrict__ src, const int* __restrict__ dst,
    int* __restrict__ pos, int* __restrict__ col)
{
  int t = blockIdx.x * 256 + threadIdx.x;
  if (t >= NE) return;
  int p = atomicAdd(&pos[dst[t]], 1);
  col[p] = src[t];
}

// ---------------- CSR gather from x plane -> bf16 agg plane ----------------
__global__ __launch_bounds__(256) void k_gather(
    const unsigned short* __restrict__ xhi, const int* __restrict__ rowptr,
    const int* __restrict__ col, unsigned short* __restrict__ agghi)
{
  int n = blockIdx.x * 4 + (threadIdx.x >> 6);
  int lane = threadIdx.x & 63;
  int c = lane >> 2, q = lane & 3;
  int lo = rowptr[n], hi = rowptr[n + 1];
  const unsigned* xp = (const unsigned*)xhi;
  float a0 = 0.f, a1 = 0.f, a2 = 0.f, a3 = 0.f;
  float b0 = 0.f, b1 = 0.f, b2 = 0.f, b3 = 0.f;
  int e = lo;
  for (; e + 3 < hi; e += 4) {
    int r0 = col[e], r1 = col[e + 1], r2 = col[e + 2], r3 = col[e + 3];
    unsigned u0 = xp[(size_t)r0 * 64 + ((c ^ (r0 & 7)) << 2) + q];
    unsigned u1 = xp[(size_t)r1 * 64 + ((c ^ (r1 & 7)) << 2) + q];
    unsigned u2 = xp[(size_t)r2 * 64 + ((c ^ (r2 & 7)) << 2) + q];
    unsigned u3 = xp[(size_t)r3 * 64 + ((c ^ (r3 & 7)) << 2) + q];
    a0 += bf16tof_((unsigned short)(u0 & 0xFFFF)); b0 += bf16tof_((unsigned short)(u0 >> 16));
    a1 += bf16tof_((unsigned short)(u1 & 0xFFFF)); b1 += bf16tof_((unsigned short)(u1 >> 16));
    a2 += bf16tof_((unsigned short)(u2 & 0xFFFF)); b2 += bf16tof_((unsigned short)(u2 >> 16));
    a3 += bf16tof_((unsigned short)(u3 & 0xFFFF)); b3 += bf16tof_((unsigned short)(u3 >> 16));
  }
  for (; e < hi; ++e) {
    int r0 = col[e];
    unsigned u0 = xp[(size_t)r0 * 64 + ((c ^ (r0 & 7)) << 2) + q];
    a0 += bf16tof_((unsigned short)(u0 & 0xFFFF));
    b0 += bf16tof_((unsigned short)(u0 >> 16));
  }
  float s0 = (a0 + a1) + (a2 + a3), s1 = (b0 + b1) + (b2 + b3);
  unsigned short h0 = bf16r_(s0), h1 = bf16r_(s1);
  size_t w = (size_t)n * 64 + ((c ^ (n & 7)) << 2) + q;
  ((unsigned*)agghi)[w] = (unsigned)h0 | ((unsigned)h1 << 16);
}

__device__ __forceinline__ int lbound_(const int* __restrict__ a, int n, int key)
{
  int lo = 0, hi = n;
  while (lo < hi) { int mid = (lo + hi) >> 1; if (a[mid] < key) lo = mid + 1; else hi = mid; }
  return lo;
}

// ---------------- graph readout -> reps split-bf16 planes ----------------
__global__ __launch_bounds__(256) void k_readout(
    const float* __restrict__ h, const float* __restrict__ wnode,
    const int* __restrict__ n2g, unsigned short* __restrict__ xplh,
    unsigned short* __restrict__ xpll, int layer)
{
  __shared__ float WS[128], HM[128];
  int g = blockIdx.x;
  int tid = threadIdx.x;
  int j = tid & 127, ty = tid >> 7;
  int lo = lbound_(n2g, NN, g);
  int hi = lbound_(n2g, NN, g + 1);
  float ws0 = 0.f, hm0 = -INFINITY, ws1 = 0.f, hm1 = -INFINITY;
  int n = lo + ty;
  for (; n + 2 < hi; n += 4) {
    float hv0 = h[(size_t)n * 128 + j];
    float hv1 = h[(size_t)(n + 2) * 128 + j];
    ws0 = fmaf(wnode[n], hv0, ws0);     hm0 = fmaxf(hm0, hv0);
    ws1 = fmaf(wnode[n + 2], hv1, ws1); hm1 = fmaxf(hm1, hv1);
  }
  if (n < hi) {
    float hv0 = h[(size_t)n * 128 + j];
    ws0 = fmaf(wnode[n], hv0, ws0); hm0 = fmaxf(hm0, hv0);
  }
  float ws = ws0 + ws1, hm = fmaxf(hm0, hm1);
  if (ty == 1) { WS[j] = ws; HM[j] = hm; }
  __syncthreads();
  if (ty == 0) {
    ws += WS[j];
    hm = fmaxf(hm, HM[j]);
    if (hi == lo) hm = 0.f;
    int r = layer * NG + g;
    {
      unsigned short hi16 = bf16r_(ws);
      unsigned short lo16 = bf16r_(ws - bf16tof_(hi16));
      size_t si = (size_t)r * 256 + (((j >> 3) ^ (r & 7)) << 3) + (j & 7);
      xplh[si] = hi16; xpll[si] = lo16;
    }
    {
      int ch = 128 + j;
      unsigned short hi16 = bf16r_(hm);
      unsigned short lo16 = bf16r_(hm - bf16tof_(hi16));
      size_t si = (size_t)r * 256 + (((ch >> 3) ^ (r & 7)) << 3) + (ch & 7);
      xplh[si] = hi16; xpll[si] = lo16;
    }
  }
}

// ---------------- persistent MFMA GRU: bf16 A-planes, exact-h epilogue ----------------
// grid 256, 8 waves. LDS: 2 x 32KB dbuf {xhi|agghi}. h_old loaded from global fp32,
// issued BEFORE the prefetch so the epilogue's vmcnt wait leaves the prefetch in flight.
__global__ __launch_bounds__(512, 2) void k_gru_mfma(
    float* __restrict__ h,
    const unsigned short* __restrict__ xhi, const unsigned short* __restrict__ agghi,
    const unsigned short* __restrict__ Wp, const float* __restrict__ bcat,
    const float* __restrict__ bnp)
{
  __shared__ alignas(16) unsigned short A[2][16384];  // 2 x 32KB
  const int tid = threadIdx.x;
  const int lane = tid & 63;
  const int wv = tid >> 6;
  const int mfr = lane & 15;
  const int kq = lane >> 4;
  const int j = wv * 16 + mfr;

  bfrag8 wreg[8][4];
#pragma unroll
  for (int kb = 0; kb < 8; ++kb) {
    int ng = (kb < 4) ? 4 : 3;
#pragma unroll
    for (int g = 0; g < 4; ++g) {
      if (g < ng) {
        int n = g * 128 + j;
        wreg[kb][g] = *(const bfrag8*)(Wp + (size_t)kb * 16384 + n * 32 + kq * 8);
      }
    }
  }

  auto stage = [&](int buf, int tile) {
    size_t goff = (size_t)tile * 64 * 128;
    const unsigned short* srcs[2] = { xhi + goff, agghi + goff };
#pragma unroll
    for (int p = 0; p < 2; ++p) {
#pragma unroll
      for (int it = 0; it < 2; ++it) {
        int off = it * 4096 + wv * 512;
        gl_lds16(srcs[p] + off + lane * 8, &A[buf][p * 8192 + off]);
      }
    }
  };

  const float sc = bnp[j], sh = bnp[128 + j];
  const float br = bcat[j], bz = bcat[128 + j], bi = bcat[256 + j], bh = bcat[384 + j];

  int tile = blockIdx.x;
  stage(0, tile);
  __syncthreads();
  int cur = 0;

  while (true) {
    int nxt = tile + GRUGRID;
    int m0 = tile * 64;

    // h_old loads for this tile: issued first (older than prefetch in vmcnt order)
    float hv[4][4];
#pragma unroll
    for (int m = 0; m < 4; ++m)
#pragma unroll
      for (int reg = 0; reg < 4; ++reg)
        hv[m][reg] = h[(size_t)(m0 + m * 16 + kq * 4 + reg) * 128 + j];

    if (nxt < NT) stage(cur ^ 1, nxt);  // async prefetch overlaps compute

    f32x4 acc[4][4];
#pragma unroll
    for (int m = 0; m < 4; ++m)
#pragma unroll
      for (int g = 0; g < 4; ++g) acc[m][g] = (f32x4){0.f, 0.f, 0.f, 0.f};

    const char* Ab = (const char*)&A[cur][0];
#pragma unroll
    for (int kb = 0; kb < 8; ++kb) {
      int kp = kb & 3;
      int hoff = (kb < 4) ? 0 : 16384;  // bytes: x plane vs agg plane
      int ng = (kb < 4) ? 4 : 3;
      bfrag8 ah[4];
#pragma unroll
      for (int m = 0; m < 4; ++m) {
        int row = m * 16 + mfr;
        int cs = (((kp * 4 + kq) ^ (row & 7)) << 4);
        ah[m] = *(const bfrag8*)(Ab + hoff + row * 256 + cs);
      }
#pragma unroll
      for (int m = 0; m < 4; ++m)
#pragma unroll
        for (int g = 0; g < 4; ++g) {
          if (g < ng)
            acc[m][g] = __builtin_amdgcn_mfma_f32_16x16x32_bf16(ah[m], wreg[kb][g], acc[m][g], 0, 0, 0);
        }
    }

    // epilogue: exact h path, fast transcendentals
#pragma unroll
    for (int m = 0; m < 4; ++m) {
#pragma unroll
      for (int reg = 0; reg < 4; ++reg) {
        int node = m0 + m * 16 + kq * 4 + reg;
        float hvv = hv[m][reg];
        float x = fmaf(hvv, sc, sh);
        float r = sig_(acc[m][0][reg] + br);
        float z = sig_(acc[m][1][reg] + bz);
        float n2 = ftanh_(fmaf(r, acc[m][3][reg] + bh, acc[m][2][reg] + bi));
        float o = (1.f - z) * n2 + z * x;
        float hc = (o > 0.f) ? o : fexpm1_(o);
        if (node < NN) h[(size_t)node * 128 + j] = hvv + hc;
      }
    }

    if (nxt >= NT) break;
    __syncthreads();  // drain prefetch + sync before buffer swap
    cur ^= 1;
    tile = nxt;
  }
}

// ---------------- x-gates precompute (LSTM, all steps fwd+bwd) ----------------
__global__ __launch_bounds__(512) void k_xgates(
    const unsigned short* __restrict__ xplh, const unsigned short* __restrict__ xpll,
    const unsigned short* __restrict__ Wihb, const unsigned short* __restrict__ Wihf,
    const float* __restrict__ bcb, const float* __restrict__ bcf,
    float* __restrict__ gxb, float* __restrict__ gxf)
{
  __shared__ alignas(16) unsigned short Ah[16384], Al[16384];
  int bid = blockIdx.x;
  const unsigned short* Wp; const float* bc; float* gx; int r0;
  if (bid < 80) { Wp = Wihb; bc = bcb; gx = gxb; r0 = bid * 64; }
  else          { Wp = Wihf; bc = bcf; gx = gxf; r0 = (bid - 80) * 64; }
  const int tid = threadIdx.x;
  const int lane = tid & 63;
  const int wv = tid >> 6;
  const int mfr = lane & 15;
  const int kq = lane >> 4;
  const int j = wv * 16 + mfr;

#pragma unroll
  for (int q = 0; q < 4; ++q) {
    int off = (q * 512 + wv * 64) * 8;
    gl_lds16(xplh + (size_t)r0 * 256 + off + lane * 8, &Ah[off]);
    gl_lds16(xpll + (size_t)r0 * 256 + off + lane * 8, &Al[off]);
  }

  bfrag8 wr[8][4];
#pragma unroll
  for (int kb = 0; kb < 8; ++kb)
#pragma unroll
    for (int g = 0; g < 4; ++g) {
      int n = g * 128 + j;
      wr[kb][g] = *(const bfrag8*)(Wp + (size_t)kb * 16384 + n * 32 + kq * 8);
    }

  __syncthreads();

  f32x4 acc[4][4];
#pragma unroll
  for (int m = 0; m < 4; ++m)
#pragma unroll
    for (int g = 0; g < 4; ++g) acc[m][g] = (f32x4){0.f, 0.f, 0.f, 0.f};

  const char* Ab = (const char*)Ah;
  const char* Al8 = (const char*)Al;
#pragma unroll
  for (int kb = 0; kb < 8; ++kb) {
    bfrag8 ah[4], al[4];
#pragma unroll
    for (int m = 0; m < 4; ++m) {
      int rr = m * 16 + mfr;
      int cs = ((((kb * 4 + kq)) ^ (rr & 7)) << 4);
      ah[m] = *(const bfrag8*)(Ab + rr * 512 + cs);
      al[m] = *(const bfrag8*)(Al8 + rr * 512 + cs);
    }
#pragma unroll
    for (int m = 0; m < 4; ++m)
#pragma unroll
      for (int g = 0; g < 4; ++g) {
        acc[m][g] = __builtin_amdgcn_mfma_f32_16x16x32_bf16(ah[m], wr[kb][g], acc[m][g], 0, 0, 0);
        acc[m][g] = __builtin_amdgcn_mfma_f32_16x16x32_bf16(al[m], wr[kb][g], acc[m][g], 0, 0, 0);
      }
  }

#pragma unroll
  for (int g = 0; g < 4; ++g) {
    float b = bc[g * 128 + j];
#pragma unroll
    for (int m = 0; m < 4; ++m)
#pragma unroll
      for (int reg = 0; reg < 4; ++reg) {
        int rr = m * 16 + kq * 4 + reg;
        gx[((size_t)(r0 + rr)) * 512 + g * 128 + j] = acc[m][g][reg] + b;
      }
  }
}

// ---------------- fwd LSTM step 0 (h0=c0=0): pure pointwise ----------------
__global__ __launch_bounds__(256) void k_lstm0(const float* __restrict__ gxf, float* __restrict__ yf)
{
  int i = blockIdx.x * 256 + threadIdx.x;
  int row = i >> 7, j = i & 127;
  const float* gp = gxf + (size_t)row * 512;
  float cn = sig_(gp[j]) * ftanh_(gp[256 + j]);
  yf[i] = sig_(gp[384 + j]) * ftanh_(cn);
}

// ---------------- bwd LSTM recurrence: 5 steps in one kernel ----------------
__global__ __launch_bounds__(512) void k_lstm_rec(
    const float* __restrict__ gxb, const unsigned short* __restrict__ Whh,
    float* __restrict__ yb)
{
  __shared__ alignas(16) unsigned short Hh[4096], Hl[4096];
  const int tid = threadIdx.x;
  const int lane = tid & 63;
  const int wv = tid >> 6;
  const int mfr = lane & 15;
  const int kq = lane >> 4;
  const int r0 = blockIdx.x * 32;
  const int j = wv * 16 + mfr;

  bfrag8 whh[4][4];
#pragma unroll
  for (int kb = 0; kb < 4; ++kb)
#pragma unroll
    for (int g = 0; g < 4; ++g) {
      int n = g * 128 + j;
      whh[kb][g] = *(const bfrag8*)(Whh + (size_t)kb * 16384 + n * 32 + kq * 8);
    }

  float cc[2][4];
#pragma unroll
  for (int m = 0; m < 2; ++m)
#pragma unroll
    for (int reg = 0; reg < 4; ++reg) {
      int rr = m * 16 + kq * 4 + reg;
      const float* gp = gxb + ((size_t)(4 * NG) + r0 + rr) * 512;
      float cn = sig_(gp[j]) * ftanh_(gp[256 + j]);
      cc[m][reg] = cn;
      float hh = sig_(gp[384 + j]) * ftanh_(cn);
      unsigned short hb16 = bf16r_(hh);
      unsigned short lb16 = bf16r_(hh - bf16tof_(hb16));
      int si = rr * 128 + (((j >> 3) ^ (rr & 7)) << 3) + (j & 7);
      Hh[si] = hb16; Hl[si] = lb16;
    }
  __syncthreads();

  for (int t = 3; t >= 0; --t) {
    f32x4 acc[2][4];
#pragma unroll
    for (int m = 0; m < 2; ++m)
#pragma unroll
      for (int g = 0; g < 4; ++g) acc[m][g] = (f32x4){0.f, 0.f, 0.f, 0.f};
    const char* Bh = (const char*)Hh;
    const char* Bl = (const char*)Hl;
#pragma unroll
    for (int kb = 0; kb < 4; ++kb) {
      bfrag8 ah[2], al[2];
#pragma unroll
      for (int m = 0; m < 2; ++m) {
        int rr = m * 16 + mfr;
        int cs = (((kb * 4 + kq) ^ (rr & 7)) << 4);
        ah[m] = *(const bfrag8*)(Bh + rr * 256 + cs);
        al[m] = *(const bfrag8*)(Bl + rr * 256 + cs);
      }
#pragma unroll
      for (int m = 0; m < 2; ++m)
#pragma unroll
        for (int g = 0; g < 4; ++g) {
          acc[m][g] = __builtin_amdgcn_mfma_f32_16x16x32_bf16(ah[m], whh[kb][g], acc[m][g], 0, 0, 0);
          acc[m][g] = __builtin_amdgcn_mfma_f32_16x16x32_bf16(al[m], whh[kb][g], acc[m][g], 0, 0, 0);
        }
    }
    __syncthreads();
#pragma unroll
    for (int m = 0; m < 2; ++m)
#pragma unroll
      for (int reg = 0; reg < 4; ++reg) {
        int rr = m * 16 + kq * 4 + reg;
        const float* gp = gxb + ((size_t)(t * NG) + r0 + rr) * 512;
        float g0 = acc[m][0][reg] + gp[j];
        float g1 = acc[m][1][reg] + gp[128 + j];
        float g2 = acc[m][2][reg] + gp[256 + j];
        float g3 = acc[m][3][reg] + gp[384 + j];
        float cn = fmaf(sig_(g1), cc[m][reg], sig_(g0) * ftanh_(g2));
        cc[m][reg] = cn;
        float hh = sig_(g3) * ftanh_(cn);
        if (t > 0) {
          unsigned short hb16 = bf16r_(hh);
          unsigned short lb16 = bf16r_(hh - bf16tof_(hb16));
          int si = rr * 128 + (((j >> 3) ^ (rr & 7)) << 3) + (j & 7);
          Hh[si] = hb16; Hl[si] = lb16;
        } else {
          yb[(size_t)(r0 + rr) * 128 + j] = hh;
        }
      }
    if (t > 0) __syncthreads();
  }
}

// ---------------- final projection ----------------
__global__ __launch_bounds__(256) void k_final(
    const float* __restrict__ yf, const float* __restrict__ yb,
    const float* __restrict__ W_out, const float* __restrict__ b_out,
    float* __restrict__ out)
{
  int tid = threadIdx.x;
  int g = blockIdx.x * 4 + (tid >> 6);
  int lane = tid & 63;
  float a0 = 0.f, a1 = 0.f;
  for (int k = lane; k < 128; k += 64) {
    float v = yf[g * 128 + k];
    a0 = fmaf(v, W_out[k * 2 + 0], a0);
    a1 = fmaf(v, W_out[k * 2 + 1], a1);
    float u = yb[g * 128 + k];
    a0 = fmaf(u, W_out[(128 + k) * 2 + 0], a0);
    a1 = fmaf(u, W_out[(128 + k) * 2 + 1], a1);
  }
#pragma unroll
  for (int o = 32; o > 0; o >>= 1) { a0 += __shfl_xor(a0, o); a1 += __shfl_xor(a1, o); }
  if (lane == 0) {
    out[g * 2 + 0] = a0 + b_out[0];
    out[g * 2 + 1] = a1 + b_out[1];
  }
}

extern "C" void kernel_launch(void* const* d_in, const int* in_sizes, int n_in,
                              void* d_out, int out_size, void* d_ws, size_t ws_size,
                              hipStream_t stream)
{
  (void)in_sizes; (void)n_in; (void)out_size; (void)ws_size;
  const float* feats   = (const float*)d_in[0];
  const int*   src     = (const int*)d_in[1];
  const int*   dst     = (const int*)d_in[2];
  const int*   n2g     = (const int*)d_in[3];
  const float* W_in    = (const float*)d_in[4];
  const float* b_in    = (const float*)d_in[5];
  const float* bng     = (const float*)d_in[6];
  const float* bnb     = (const float*)d_in[7];
  const float* bnm     = (const float*)d_in[8];
  const float* bnv     = (const float*)d_in[9];
  const float* gw_ih   = (const float*)d_in[10];
  const float* gw_hh   = (const float*)d_in[11];
  const float* gb_ih   = (const float*)d_in[12];
  const float* gb_hh   = (const float*)d_in[13];
  const float* w_aw    = (const float*)d_in[14];
  const float* b_aw    = (const float*)d_in[15];
  const float* lwih_f  = (const float*)d_in[16];
  const float* lwhh_f  = (const float*)d_in[17];
  const float* lbih_f  = (const float*)d_in[18];
  const float* lbhh_f  = (const float*)d_in[19];
  const float* lwih_b  = (const float*)d_in[20];
  const float* lwhh_b  = (const float*)d_in[21];
  const float* lbih_b  = (const float*)d_in[22];
  const float* lbhh_b  = (const float*)d_in[23];
  const float* W_out   = (const float*)d_in[24];
  const float* b_out   = (const float*)d_in[25];
  float* out = (float*)d_out;
  (void)lwhh_f;  // fwd w_hh unused: h0=0, only fwd step 0 needed

  float* ws = (float*)d_ws;
  size_t off = 0;
  auto alloc = [&](size_t n) { float* p = ws + off; off += (n + 63) & ~(size_t)63; return p; };
  float* h      = alloc((size_t)NP * 128);
  unsigned short* xhi   = (unsigned short*)alloc((size_t)NP * 64);
  unsigned short* agghi = (unsigned short*)alloc((size_t)NP * 64);
  unsigned short* Wp    = (unsigned short*)alloc(65536);
  float* bcat   = alloc(512);
  float* wnode  = alloc(NN);
  float* bnp    = alloc(NL * 256);
  unsigned short* xplh = (unsigned short*)alloc((size_t)NL * NG * 128);
  unsigned short* xpll = (unsigned short*)alloc((size_t)NL * NG * 128);
  unsigned short* Wihf = (unsigned short*)alloc(65536);
  unsigned short* Wihb = (unsigned short*)alloc(65536);
  unsigned short* Whhb = (unsigned short*)alloc(32768);
  float* bcf    = alloc(512);
  float* bcb    = alloc(512);
  float* gxb    = alloc((size_t)NL * NG * 512);
  float* gxf    = alloc((size_t)NG * 512);
  float* yf     = alloc((size_t)NG * 128);
  float* yb     = alloc((size_t)NG * 128);
  int* deg    = (int*)alloc(NN);
  int* rowptr = (int*)alloc(NN + 1);
  int* pos    = (int*)alloc(NN);
  int* colidx = (int*)alloc(NE);
  int* bsum   = (int*)alloc(256);
  int* boff   = (int*)alloc(256);

  // ---- one-time: CSR build + weight prepacks + BN prep ----
  hipMemsetAsync(deg, 0, (size_t)NN * sizeof(int), stream);
  k_hist<<<(NE + 255) / 256, 256, 0, stream>>>(dst, deg);
  k_scan1<<<196, 256, 0, stream>>>(deg, bsum);
  k_scan2<<<1, 256, 0, stream>>>(bsum, boff, rowptr);
  k_scan3<<<196, 256, 0, stream>>>(deg, boff, rowptr);
  hipMemcpyAsync(pos, rowptr, (size_t)NN * sizeof(int), hipMemcpyDeviceToDevice, stream);
  k_fill<<<(NE + 255) / 256, 256, 0, stream>>>(src, dst, pos, colidx);
  k_wpack<<<512, 256, 0, stream>>>(gw_ih, gw_hh, gb_ih, gb_hh, Wp, bcat);
  k_wpack_lstm<<<1280, 256, 0, stream>>>(lwih_f, lwih_b, lwhh_b, lbih_f, lbhh_f, lbih_b, lbhh_b,
                                         Wihf, Wihb, Whhb, bcf, bcb);
  k_bnprep_all<<<NL, 128, 0, stream>>>(bng, bnb, bnm, bnv, bnp);

  k_input_proj<<<1024, 256, 0, stream>>>(feats, W_in, b_in, h);

  for (int l = 0; l < NL; ++l) {
    const float* bnpl = bnp + l * 256;
    k_prep<<<3125, 256, 0, stream>>>(h, bnpl, w_aw, b_aw, xhi, wnode);
    k_gather<<<NN / 4, 256, 0, stream>>>(xhi, rowptr, colidx, agghi);
    k_readout<<<NG, 256, 0, stream>>>(h, wnode, n2g, xplh, xpll, l);
    k_gru_mfma<<<GRUGRID, 512, 0, stream>>>(h, xhi, agghi, Wp, bcat, bnpl);
  }

  // ---- LSTM: x-gates then recurrence ----
  k_xgates<<<96, 512, 0, stream>>>(xplh, xpll, Wihb, Wihf, bcb, bcf, gxb, gxf);
  k_lstm0<<<512, 256, 0, stream>>>(gxf, yf);
  k_lstm_rec<<<32, 512, 0, stream>>>(gxb, Whhb, yb);

  k_final<<<NG / 4, 256, 0, stream>>>(yf, yb, W_out, b_out, out);
}

// Round 9
// 565.968 us; speedup vs baseline: 1.1912x; 1.1912x over previous
//
#include <hip/hip_runtime.h>
#include <math.h>

#define NN 50000
#define NP 50048   // padded rows (multiple of 64)
#define NE 600000
#define NG 1024
#define NL 5
#define NT (NP / 64)     // 782 M-tiles
#define GRUGRID 256      // persistent blocks (1 per CU)
// Hd = 128, Fin = 74, C = 2

typedef __attribute__((ext_vector_type(8))) short bfrag8;
typedef __attribute__((ext_vector_type(4))) float f32x4;

// ---- fast transcendentals (v_exp_f32 / v_rcp_f32; abs err ~1e-6, budget 1.4e-2) ----
__device__ __forceinline__ float fexp_(float x) { return __builtin_amdgcn_exp2f(x * 1.44269504f); }
__device__ __forceinline__ float sig_(float x)  { return __builtin_amdgcn_rcpf(1.f + fexp_(-x)); }
__device__ __forceinline__ float ftanh_(float x){ return fmaf(2.f, __builtin_amdgcn_rcpf(1.f + fexp_(-2.f * x)), -1.f); }
__device__ __forceinline__ float fexpm1_(float x){ return fexp_(x) - 1.f; }

__device__ __forceinline__ unsigned short bf16r_(float x) {
  union { float f; unsigned u; } v; v.f = x;
  unsigned u = v.u;
  return (unsigned short)((u + 0x7FFFu + ((u >> 16) & 1u)) >> 16);
}
__device__ __forceinline__ float bf16tof_(unsigned short h) {
  union { float f; unsigned u; } v; v.u = ((unsigned)h) << 16;
  return v.f;
}

// async global->LDS, 16B per lane; lds dst = uniform base + lane*16
__device__ __forceinline__ void gl_lds16(const unsigned short* g, unsigned short* l) {
  __builtin_amdgcn_global_load_lds(
      (const __attribute__((address_space(1))) unsigned int*)g,
      (__attribute__((address_space(3))) unsigned int*)l, 16, 0, 0);
}

// ---------------- input projection: h = feats @ W_in + b_in ----------------
__global__ __launch_bounds__(256) void k_input_proj(
    const float* __restrict__ feats, const float* __restrict__ W_in,
    const float* __restrict__ b_in, float* __restrict__ h)
{
  const int j = threadIdx.x & 127;
  const int half = threadIdx.x >> 7;   // wave-uniform
  float wcol[74];
#pragma unroll
  for (int k = 0; k < 74; ++k) wcol[k] = W_in[k * 128 + j];
  const float bj = b_in[j];
  for (int p = blockIdx.x; p < NN / 2; p += gridDim.x) {
    int node = __builtin_amdgcn_readfirstlane(p * 2 + half);
    const float* fr = feats + (size_t)node * 74;
    float acc = bj;
#pragma unroll
    for (int k = 0; k < 74; ++k) acc = fmaf(fr[k], wcol[k], acc);
    h[(size_t)node * 128 + j] = acc;
  }
}

// ---------------- per-layer BN scale/shift precompute (all layers) ----------------
__global__ void k_bnprep_all(const float* __restrict__ g, const float* __restrict__ b,
                             const float* __restrict__ m, const float* __restrict__ v,
                             float* __restrict__ bnp)
{
  int l = blockIdx.x;
  int j = threadIdx.x;
  float s = g[l * 128 + j] * rsqrtf(v[l * 128 + j] + 1e-5f);
  bnp[l * 256 + j] = s;
  bnp[l * 256 + 128 + j] = b[l * 128 + j] - m[l * 128 + j] * s;
}

// ---------------- GRU weight prepack ----------------
__global__ __launch_bounds__(256) void k_wpack(
    const float* __restrict__ w_ih, const float* __restrict__ w_hh,
    const float* __restrict__ b_ih, const float* __restrict__ b_hh,
    unsigned short* __restrict__ Wp, float* __restrict__ bcat)
{
  int idx = blockIdx.x * 256 + threadIdx.x;
  int n = idx >> 8, k = idx & 255;
  float val;
  if (n < 256) {
    val = (k < 128) ? fmaf(1.00001f, w_ih[n * 256 + k], w_hh[n * 128 + k])
                    : w_ih[n * 256 + k];
  } else if (n < 384) {
    val = (k < 128) ? 1.00001f * w_ih[n * 256 + k] : w_ih[n * 256 + k];
  } else {
    int g = n - 128;
    val = (k < 128) ? w_hh[g * 128 + k] : 0.f;
  }
  Wp[(size_t)(k >> 5) * 16384 + n * 32 + (k & 31)] = bf16r_(val);
  if (k == 0) {
    float bc;
    if (n < 256) bc = b_ih[n] + b_hh[n];
    else if (n < 384) bc = b_ih[n];
    else bc = b_hh[n - 128];
    bcat[n] = bc;
  }
}

// ---------------- LSTM weight prepack ----------------
__global__ __launch_bounds__(256) void k_wpack_lstm(
    const float* __restrict__ lwih_f, const float* __restrict__ lwih_b,
    const float* __restrict__ lwhh_b,
    const float* __restrict__ lbih_f, const float* __restrict__ lbhh_f,
    const float* __restrict__ lbih_b, const float* __restrict__ lbhh_b,
    unsigned short* __restrict__ Wihf, unsigned short* __restrict__ Wihb,
    unsigned short* __restrict__ Whhb, float* __restrict__ bcf, float* __restrict__ bcb)
{
  int idx = blockIdx.x * 256 + threadIdx.x;
  if (idx < 131072) {
    int n = idx >> 8, k = idx & 255;
    Wihf[(size_t)(k >> 5) * 16384 + n * 32 + (k & 31)] = bf16r_(lwih_f[n * 256 + k]);
  } else if (idx < 262144) {
    int i2 = idx - 131072; int n = i2 >> 8, k = i2 & 255;
    Wihb[(size_t)(k >> 5) * 16384 + n * 32 + (k & 31)] = bf16r_(lwih_b[n * 256 + k]);
  } else if (idx < 327680) {
    int i2 = idx - 262144; int n = i2 >> 7, k = i2 & 127;
    Whhb[(size_t)(k >> 5) * 16384 + n * 32 + (k & 31)] = bf16r_(lwhh_b[n * 128 + k]);
  }
  if (idx < 512) {
    bcf[idx] = lbih_f[idx] + lbhh_f[idx];
    bcb[idx] = lbih_b[idx] + lbhh_b[idx];
  }
}

// ---------------- prep: x = BN(h) -> swizzled bf16 plane; + wnode ----------------
__global__ __launch_bounds__(256) void k_prep(
    const float* __restrict__ h, const float* __restrict__ bnp,
    const float* __restrict__ w_aw, const float* __restrict__ b_aw,
    unsigned short* __restrict__ xhi, float* __restrict__ wnode)
{
  int t = blockIdx.x * 256 + threadIdx.x;
  int row = t >> 4, c = t & 15;
  const float* hp = h + (size_t)row * 128 + c * 8;
  float4 h0 = *(const float4*)(hp);
  float4 h1 = *(const float4*)(hp + 4);
  float4 s0 = *(const float4*)(bnp + c * 8);
  float4 s1 = *(const float4*)(bnp + c * 8 + 4);
  float4 t0 = *(const float4*)(bnp + 128 + c * 8);
  float4 t1 = *(const float4*)(bnp + 128 + c * 8 + 4);
  float x[8] = { fmaf(h0.x, s0.x, t0.x), fmaf(h0.y, s0.y, t0.y),
                 fmaf(h0.z, s0.z, t0.z), fmaf(h0.w, s0.w, t0.w),
                 fmaf(h1.x, s1.x, t1.x), fmaf(h1.y, s1.y, t1.y),
                 fmaf(h1.z, s1.z, t1.z), fmaf(h1.w, s1.w, t1.w) };
  unsigned hiw[4];
#pragma unroll
  for (int i = 0; i < 4; ++i) {
    unsigned short ha = bf16r_(x[2 * i]), hb = bf16r_(x[2 * i + 1]);
    hiw[i] = (unsigned)ha | ((unsigned)hb << 16);
  }
  size_t dst = (size_t)row * 16 + (c ^ (row & 7));
  ((uint4*)xhi)[dst] = make_uint4(hiw[0], hiw[1], hiw[2], hiw[3]);
  const float4 wa0 = *(const float4*)(w_aw + c * 8);
  const float4 wa1 = *(const float4*)(w_aw + c * 8 + 4);
  float p = h0.x * wa0.x + h0.y * wa0.y + h0.z * wa0.z + h0.w * wa0.w +
            h1.x * wa1.x + h1.y * wa1.y + h1.z * wa1.z + h1.w * wa1.w;
#pragma unroll
  for (int o = 8; o > 0; o >>= 1) p += __shfl_xor(p, o);
  if (c == 0) wnode[row] = sig_(p + b_aw[0]);
}

// ---------------- CSR build ----------------
__global__ __launch_bounds__(256) void k_hist(const int* __restrict__ dst, int* __restrict__ deg)
{
  int t = blockIdx.x * 256 + threadIdx.x;
  if (t < NE) atomicAdd(&deg[dst[t]], 1);
}

__global__ __launch_bounds__(256) void k_scan1(const int* __restrict__ deg, int* __restrict__ bsum)
{
  __shared__ int red[4];
  int i = blockIdx.x * 256 + threadIdx.x;
  int d = (i < NN) ? deg[i] : 0;
  int s = d;
#pragma unroll
  for (int o = 32; o > 0; o >>= 1) s += __shfl_xor(s, o);
  if ((threadIdx.x & 63) == 0) red[threadIdx.x >> 6] = s;
  __syncthreads();
  if (threadIdx.x == 0) bsum[blockIdx.x] = red[0] + red[1] + red[2] + red[3];
}

__global__ __launch_bounds__(256) void k_scan2(const int* __restrict__ bsum, int* __restrict__ boff,
                                               int* __restrict__ rowptr)
{
  __shared__ int part[256];
  int t = threadIdx.x;
  int v = (t < 196) ? bsum[t] : 0;
  part[t] = v;
  __syncthreads();
  for (int o = 1; o < 256; o <<= 1) {
    int u = (t >= o) ? part[t - o] : 0;
    __syncthreads();
    part[t] += u;
    __syncthreads();
  }
  if (t < 196) boff[t] = part[t] - v;
  if (t == 0) rowptr[NN] = NE;
}

__global__ __launch_bounds__(256) void k_scan3(const int* __restrict__ deg, const int* __restrict__ boff,
                                               int* __restrict__ rowptr)
{
  __shared__ int part[256];
  int t = threadIdx.x;
  int i = blockIdx.x * 256 + t;
  int d = (i < NN) ? deg[i] : 0;
  part[t] = d;
  __syncthreads();
  for (int o = 1; o < 256; o <<= 1) {
    int u = (t >= o) ? part[t - o] : 0;
    __syncthreads();
    part[t] += u;
    __syncthreads();
  }
  if (i < NN) rowptr[i] = boff[blockIdx.x] + part[t] - d;
}

__global__ __launch_bounds__(256) void k_fill(
    const int* __restrict__ src, const int* __restrict__ dst,
    int* __restrict__ pos, int* __restrict__ col)
{
  int t = blockIdx.x * 256 + threadIdx.x;
  if (t >= NE) return;
  int p = atomicAdd(&pos[dst[t]], 1);
  col[p] = src[t];
}

// ---------------- CSR gather from x plane -> bf16 agg plane ----------------
__global__ __launch_bounds__(256) void k_gather(
    const unsigned short* __restrict__ xhi, const int* __restrict__ rowptr,
    const int* __restrict__ col, unsigned short* __restrict__ agghi)
{
  int n = blockIdx.x * 4 + (threadIdx.x >> 6);
  int lane = threadIdx.x & 63;
  int c = lane >> 2, q = lane & 3;
  int lo = rowptr[n], hi = rowptr[n + 1];
  const unsigned* xp = (const unsigned*)xhi;
  float a0 = 0.f, a1 = 0.f, a2 = 0.f, a3 = 0.f;
  float b0 = 0.f, b1 = 0.f, b2 = 0.f, b3 = 0.f;
  int e = lo;
  for (; e + 3 < hi; e += 4) {
    int r0 = col[e], r1 = col[e + 1], r2 = col[e + 2], r3 = col[e + 3];
    unsigned u0 = xp[(size_t)r0 * 64 + ((c ^ (r0 & 7)) << 2) + q];
    unsigned u1 = xp[(size_t)r1 * 64 + ((c ^ (r1 & 7)) << 2) + q];
    unsigned u2 = xp[(size_t)r2 * 64 + ((c ^ (r2 & 7)) << 2) + q];
    unsigned u3 = xp[(size_t)r3 * 64 + ((c ^ (r3 & 7)) << 2) + q];
    a0 += bf16tof_((unsigned short)(u0 & 0xFFFF)); b0 += bf16tof_((unsigned short)(u0 >> 16));
    a1 += bf16tof_((unsigned short)(u1 & 0xFFFF)); b1 += bf16tof_((unsigned short)(u1 >> 16));
    a2 += bf16tof_((unsigned short)(u2 & 0xFFFF)); b2 += bf16tof_((unsigned short)(u2 >> 16));
    a3 += bf16tof_((unsigned short)(u3 & 0xFFFF)); b3 += bf16tof_((unsigned short)(u3 >> 16));
  }
  for (; e < hi; ++e) {
    int r0 = col[e];
    unsigned u0 = xp[(size_t)r0 * 64 + ((c ^ (r0 & 7)) << 2) + q];
    a0 += bf16tof_((unsigned short)(u0 & 0xFFFF));
    b0 += bf16tof_((unsigned short)(u0 >> 16));
  }
  float s0 = (a0 + a1) + (a2 + a3), s1 = (b0 + b1) + (b2 + b3);
  unsigned short h0 = bf16r_(s0), h1 = bf16r_(s1);
  size_t w = (size_t)n * 64 + ((c ^ (n & 7)) << 2) + q;
  ((unsigned*)agghi)[w] = (unsigned)h0 | ((unsigned)h1 << 16);
}

__device__ __forceinline__ int lbound_(const int* __restrict__ a, int n, int key)
{
  int lo = 0, hi = n;
  while (lo < hi) { int mid = (lo + hi) >> 1; if (a[mid] < key) lo = mid + 1; else hi = mid; }
  return lo;
}

// ---------------- graph readout -> reps split-bf16 planes ----------------
__global__ __launch_bounds__(256) void k_readout(
    const float* __restrict__ h, const float* __restrict__ wnode,
    const int* __restrict__ n2g, unsigned short* __restrict__ xplh,
    unsigned short* __restrict__ xpll, int layer)
{
  __shared__ float WS[128], HM[128];
  int g = blockIdx.x;
  int tid = threadIdx.x;
  int j = tid & 127, ty = tid >> 7;
  int lo = lbound_(n2g, NN, g);
  int hi = lbound_(n2g, NN, g + 1);
  float ws0 = 0.f, hm0 = -INFINITY, ws1 = 0.f, hm1 = -INFINITY;
  int n = lo + ty;
  for (; n + 2 < hi; n += 4) {
    float hv0 = h[(size_t)n * 128 + j];
    float hv1 = h[(size_t)(n + 2) * 128 + j];
    ws0 = fmaf(wnode[n], hv0, ws0);     hm0 = fmaxf(hm0, hv0);
    ws1 = fmaf(wnode[n + 2], hv1, ws1); hm1 = fmaxf(hm1, hv1);
  }
  if (n < hi) {
    float hv0 = h[(size_t)n * 128 + j];
    ws0 = fmaf(wnode[n], hv0, ws0); hm0 = fmaxf(hm0, hv0);
  }
  float ws = ws0 + ws1, hm = fmaxf(hm0, hm1);
  if (ty == 1) { WS[j] = ws; HM[j] = hm; }
  __syncthreads();
  if (ty == 0) {
    ws += WS[j];
    hm = fmaxf(hm, HM[j]);
    if (hi == lo) hm = 0.f;
    int r = layer * NG + g;
    {
      unsigned short hi16 = bf16r_(ws);
      unsigned short lo16 = bf16r_(ws - bf16tof_(hi16));
      size_t si = (size_t)r * 256 + (((j >> 3) ^ (r & 7)) << 3) + (j & 7);
      xplh[si] = hi16; xpll[si] = lo16;
    }
    {
      int ch = 128 + j;
      unsigned short hi16 = bf16r_(hm);
      unsigned short lo16 = bf16r_(hm - bf16tof_(hi16));
      size_t si = (size_t)r * 256 + (((ch >> 3) ^ (r & 7)) << 3) + (ch & 7);
      xplh[si] = hi16; xpll[si] = lo16;
    }
  }
}

// ---------------- persistent MFMA GRU: bf16 A-planes, exact-h, coalesced h write ----------------
// grid 256, 8 waves, LDS 2x32KB dbuf {xhi|agghi}. h_old: scattered reg loads (latency-hidden).
// h_new: computed in regs -> staged into the dead A[cur] buffer (swizzled) -> coalesced
// dwordx4 flush (full 128B lines, no RFO). Barriers: B1 done-reading-A[cur] (+vmcnt drain),
// B2 staging complete, B3 flush ds_reads done before next prefetch overwrites A[cur].
__global__ __launch_bounds__(512, 2) void k_gru_mfma(
    float* __restrict__ h,
    const unsigned short* __restrict__ xhi, const unsigned short* __restrict__ agghi,
    const unsigned short* __restrict__ Wp, const float* __restrict__ bcat,
    const float* __restrict__ bnp)
{
  __shared__ alignas(16) unsigned short A[2][16384];  // 2 x 32KB
  const int tid = threadIdx.x;
  const int lane = tid & 63;
  const int wv = tid >> 6;
  const int mfr = lane & 15;
  const int kq = lane >> 4;
  const int j = wv * 16 + mfr;

  bfrag8 wreg[8][4];
#pragma unroll
  for (int kb = 0; kb < 8; ++kb) {
    int ng = (kb < 4) ? 4 : 3;
#pragma unroll
    for (int g = 0; g < 4; ++g) {
      if (g < ng) {
        int n = g * 128 + j;
        wreg[kb][g] = *(const bfrag8*)(Wp + (size_t)kb * 16384 + n * 32 + kq * 8);
      }
    }
  }

  auto stage = [&](int buf, int tile) {
    size_t goff = (size_t)tile * 64 * 128;
    const unsigned short* srcs[2] = { xhi + goff, agghi + goff };
#pragma unroll
    for (int p = 0; p < 2; ++p) {
#pragma unroll
      for (int it = 0; it < 2; ++it) {
        int off = it * 4096 + wv * 512;
        gl_lds16(srcs[p] + off + lane * 8, &A[buf][p * 8192 + off]);
      }
    }
  };

  const float sc = bnp[j], sh = bnp[128 + j];
  const float br = bcat[j], bz = bcat[128 + j], bi = bcat[256 + j], bh = bcat[384 + j];

  int tile = blockIdx.x;
  stage(0, tile);
  __syncthreads();
  int cur = 0;

  while (true) {
    int nxt = tile + GRUGRID;
    int m0 = tile * 64;

    // h_old scattered loads (issued first; complete by B1; overlapped with MFMA)
    float hvr[4][4];
#pragma unroll
    for (int m = 0; m < 4; ++m)
#pragma unroll
      for (int reg = 0; reg < 4; ++reg)
        hvr[m][reg] = h[(size_t)(m0 + m * 16 + kq * 4 + reg) * 128 + j];

    if (nxt < NT) stage(cur ^ 1, nxt);  // async prefetch

    f32x4 acc[4][4];
#pragma unroll
    for (int m = 0; m < 4; ++m)
#pragma unroll
      for (int g = 0; g < 4; ++g) acc[m][g] = (f32x4){0.f, 0.f, 0.f, 0.f};

    const char* Ab = (const char*)&A[cur][0];
#pragma unroll
    for (int kb = 0; kb < 8; ++kb) {
      int kp = kb & 3;
      int hoff = (kb < 4) ? 0 : 16384;
      int ng = (kb < 4) ? 4 : 3;
      bfrag8 ah[4];
#pragma unroll
      for (int m = 0; m < 4; ++m) {
        int row = m * 16 + mfr;
        int cs = (((kp * 4 + kq) ^ (row & 7)) << 4);
        ah[m] = *(const bfrag8*)(Ab + hoff + row * 256 + cs);
      }
#pragma unroll
      for (int m = 0; m < 4; ++m)
#pragma unroll
        for (int g = 0; g < 4; ++g) {
          if (g < ng)
            acc[m][g] = __builtin_amdgcn_mfma_f32_16x16x32_bf16(ah[m], wreg[kb][g], acc[m][g], 0, 0, 0);
        }
    }

    // epilogue compute in registers (overlaps other waves still in MFMA)
    float hnew[4][4];
#pragma unroll
    for (int m = 0; m < 4; ++m) {
#pragma unroll
      for (int reg = 0; reg < 4; ++reg) {
        float hvv = hvr[m][reg];
        float x = fmaf(hvv, sc, sh);
        float r = sig_(acc[m][0][reg] + br);
        float z = sig_(acc[m][1][reg] + bz);
        float n2 = ftanh_(fmaf(r, acc[m][3][reg] + bh, acc[m][2][reg] + bi));
        float o = (1.f - z) * n2 + z * x;
        float hc = (o > 0.f) ? o : fexpm1_(o);
        hnew[m][reg] = hvv + hc;
      }
    }

    __syncthreads();  // B1: all waves done reading A[cur]; hv + prefetch retired

    // stage h_new into dead A[cur] (fp32 [64][128], word-swizzled: 2-way banks)
    float* Hst = (float*)&A[cur][0];
#pragma unroll
    for (int m = 0; m < 4; ++m)
#pragma unroll
      for (int reg = 0; reg < 4; ++reg) {
        int nl = m * 16 + kq * 4 + reg;
        Hst[nl * 128 + (j ^ ((nl & 7) << 2))] = hnew[m][reg];
      }

    __syncthreads();  // B2: staging complete

    // coalesced flush: full-line dwordx4 stores (pad rows are workspace)
    {
      float* dst = h + (size_t)m0 * 128;
#pragma unroll
      for (int p = 0; p < 4; ++p) {
        int b = p * 2048 + tid * 4;   // word index in 8192-word tile
        int row = b >> 7;
        int off = b & 127;
        float4 v = *(const float4*)&Hst[row * 128 + (off ^ ((row & 7) << 2))];
        *(float4*)&dst[b] = v;
      }
    }

    if (nxt >= NT) break;
    __syncthreads();  // B3: flush ds_reads done before next prefetch overwrites A[cur]
    cur ^= 1;
    tile = nxt;
  }
}

// ---------------- x-gates precompute (LSTM, all steps fwd+bwd) ----------------
__global__ __launch_bounds__(512) void k_xgates(
    const unsigned short* __restrict__ xplh, const unsigned short* __restrict__ xpll,
    const unsigned short* __restrict__ Wihb, const unsigned short* __restrict__ Wihf,
    const float* __restrict__ bcb, const float* __restrict__ bcf,
    float* __restrict__ gxb, float* __restrict__ gxf)
{
  __shared__ alignas(16) unsigned short Ah[16384], Al[16384];
  int bid = blockIdx.x;
  const unsigned short* Wp; const float* bc; float* gx; int r0;
  if (bid < 80) { Wp = Wihb; bc = bcb; gx = gxb; r0 = bid * 64; }
  else          { Wp = Wihf; bc = bcf; gx = gxf; r0 = (bid - 80) * 64; }
  const int tid = threadIdx.x;
  const int lane = tid & 63;
  const int wv = tid >> 6;
  const int mfr = lane & 15;
  const int kq = lane >> 4;
  const int j = wv * 16 + mfr;

#pragma unroll
  for (int q = 0; q < 4; ++q) {
    int off = (q * 512 + wv * 64) * 8;
    gl_lds16(xplh + (size_t)r0 * 256 + off + lane * 8, &Ah[off]);
    gl_lds16(xpll + (size_t)r0 * 256 + off + lane * 8, &Al[off]);
  }

  bfrag8 wr[8][4];
#pragma unroll
  for (int kb = 0; kb < 8; ++kb)
#pragma unroll
    for (int g = 0; g < 4; ++g) {
      int n = g * 128 + j;
      wr[kb][g] = *(const bfrag8*)(Wp + (size_t)kb * 16384 + n * 32 + kq * 8);
    }

  __syncthreads();

  f32x4 acc[4][4];
#pragma unroll
  for (int m = 0; m < 4; ++m)
#pragma unroll
    for (int g = 0; g < 4; ++g) acc[m][g] = (f32x4){0.f, 0.f, 0.f, 0.f};

  const char* Ab = (const char*)Ah;
  const char* Al8 = (const char*)Al;
#pragma unroll
  for (int kb = 0; kb < 8; ++kb) {
    bfrag8 ah[4], al[4];
#pragma unroll
    for (int m = 0; m < 4; ++m) {
      int rr = m * 16 + mfr;
      int cs = ((((kb * 4 + kq)) ^ (rr & 7)) << 4);
      ah[m] = *(const bfrag8*)(Ab + rr * 512 + cs);
      al[m] = *(const bfrag8*)(Al8 + rr * 512 + cs);
    }
#pragma unroll
    for (int m = 0; m < 4; ++m)
#pragma unroll
      for (int g = 0; g < 4; ++g) {
        acc[m][g] = __builtin_amdgcn_mfma_f32_16x16x32_bf16(ah[m], wr[kb][g], acc[m][g], 0, 0, 0);
        acc[m][g] = __builtin_amdgcn_mfma_f32_16x16x32_bf16(al[m], wr[kb][g], acc[m][g], 0, 0, 0);
      }
  }

#pragma unroll
  for (int g = 0; g < 4; ++g) {
    float b = bc[g * 128 + j];
#pragma unroll
    for (int m = 0; m < 4; ++m)
#pragma unroll
      for (int reg = 0; reg < 4; ++reg) {
        int rr = m * 16 + kq * 4 + reg;
        gx[((size_t)(r0 + rr)) * 512 + g * 128 + j] = acc[m][g][reg] + b;
      }
  }
}

// ---------------- fwd LSTM step 0 (h0=c0=0): pure pointwise ----------------
__global__ __launch_bounds__(256) void k_lstm0(const float* __restrict__ gxf, float* __restrict__ yf)
{
  int i = blockIdx.x * 256 + threadIdx.x;
  int row = i >> 7, j = i & 127;
  const float* gp = gxf + (size_t)row * 512;
  float cn = sig_(gp[j]) * ftanh_(gp[256 + j]);
  yf[i] = sig_(gp[384 + j]) * ftanh_(cn);
}

// ---------------- bwd LSTM recurrence: 5 steps in one kernel ----------------
__global__ __launch_bounds__(512) void k_lstm_rec(
    const float* __restrict__ gxb, const unsigned short* __restrict__ Whh,
    float* __restrict__ yb)
{
  __shared__ alignas(16) unsigned short Hh[4096], Hl[4096];
  const int tid = threadIdx.x;
  const int lane = tid & 63;
  const int wv = tid >> 6;
  const int mfr = lane & 15;
  const int kq = lane >> 4;
  const int r0 = blockIdx.x * 32;
  const int j = wv * 16 + mfr;

  bfrag8 whh[4][4];
#pragma unroll
  for (int kb = 0; kb < 4; ++kb)
#pragma unroll
    for (int g = 0; g < 4; ++g) {
      int n = g * 128 + j;
      whh[kb][g] = *(const bfrag8*)(Whh + (size_t)kb * 16384 + n * 32 + kq * 8);
    }

  float cc[2][4];
#pragma unroll
  for (int m = 0; m < 2; ++m)
#pragma unroll
    for (int reg = 0; reg < 4; ++reg) {
      int rr = m * 16 + kq * 4 + reg;
      const float* gp = gxb + ((size_t)(4 * NG) + r0 + rr) * 512;
      float cn = sig_(gp[j]) * ftanh_(gp[256 + j]);
      cc[m][reg] = cn;
      float hh = sig_(gp[384 + j]) * ftanh_(cn);
      unsigned short hb16 = bf16r_(hh);
      unsigned short lb16 = bf16r_(hh - bf16tof_(hb16));
      int si = rr * 128 + (((j >> 3) ^ (rr & 7)) << 3) + (j & 7);
      Hh[si] = hb16; Hl[si] = lb16;
    }
  __syncthreads();

  for (int t = 3; t >= 0; --t) {
    f32x4 acc[2][4];
#pragma unroll
    for (int m = 0; m < 2; ++m)
#pragma unroll
      for (int g = 0; g < 4; ++g) acc[m][g] = (f32x4){0.f, 0.f, 0.f, 0.f};
    const char* Bh = (const char*)Hh;
    const char* Bl = (const char*)Hl;
#pragma unroll
    for (int kb = 0; kb < 4; ++kb) {
      bfrag8 ah[2], al[2];
#pragma unroll
      for (int m = 0; m < 2; ++m) {
        int rr = m * 16 + mfr;
        int cs = (((kb * 4 + kq) ^ (rr & 7)) << 4);
        ah[m] = *(const bfrag8*)(Bh + rr * 256 + cs);
        al[m] = *(const bfrag8*)(Bl + rr * 256 + cs);
      }
#pragma unroll
      for (int m = 0; m < 2; ++m)
#pragma unroll
        for (int g = 0; g < 4; ++g) {
          acc[m][g] = __builtin_amdgcn_mfma_f32_16x16x32_bf16(ah[m], whh[kb][g], acc[m][g], 0, 0, 0);
          acc[m][g] = __builtin_amdgcn_mfma_f32_16x16x32_bf16(al[m], whh[kb][g], acc[m][g], 0, 0, 0);
        }
    }
    __syncthreads();
#pragma unroll
    for (int m = 0; m < 2; ++m)
#pragma unroll
      for (int reg = 0; reg < 4; ++reg) {
        int rr = m * 16 + kq * 4 + reg;
        const float* gp = gxb + ((size_t)(t * NG) + r0 + rr) * 512;
        float g0 = acc[m][0][reg] + gp[j];
        float g1 = acc[m][1][reg] + gp[128 + j];
        float g2 = acc[m][2][reg] + gp[256 + j];
        float g3 = acc[m][3][reg] + gp[384 + j];
        float cn = fmaf(sig_(g1), cc[m][reg], sig_(g0) * ftanh_(g2));
        cc[m][reg] = cn;
        float hh = sig_(g3) * ftanh_(cn);
        if (t > 0) {
          unsigned short hb16 = bf16r_(hh);
          unsigned short lb16 = bf16r_(hh - bf16tof_(hb16));
          int si = rr * 128 + (((j >> 3) ^ (rr & 7)) << 3) + (j & 7);
          Hh[si] = hb16; Hl[si] = lb16;
        } else {
          yb[(size_t)(r0 + rr) * 128 + j] = hh;
        }
      }
    if (t > 0) __syncthreads();
  }
}

// ---------------- final projection ----------------
__global__ __launch_bounds__(256) void k_final(
    const float* __restrict__ yf, const float* __restrict__ yb,
    const float* __restrict__ W_out, const float* __restrict__ b_out,
    float* __restrict__ out)
{
  int tid = threadIdx.x;
  int g = blockIdx.x * 4 + (tid >> 6);
  int lane = tid & 63;
  float a0 = 0.f, a1 = 0.f;
  for (int k = lane; k < 128; k += 64) {
    float v = yf[g * 128 + k];
    a0 = fmaf(v, W_out[k * 2 + 0], a0);
    a1 = fmaf(v, W_out[k * 2 + 1], a1);
    float u = yb[g * 128 + k];
    a0 = fmaf(u, W_out[(128 + k) * 2 + 0], a0);
    a1 = fmaf(u, W_out[(128 + k) * 2 + 1], a1);
  }
#pragma unroll
  for (int o = 32; o > 0; o >>= 1) { a0 += __shfl_xor(a0, o); a1 += __shfl_xor(a1, o); }
  if (lane == 0) {
    out[g * 2 + 0] = a0 + b_out[0];
    out[g * 2 + 1] = a1 + b_out[1];
  }
}

extern "C" void kernel_launch(void* const* d_in, const int* in_sizes, int n_in,
                              void* d_out, int out_size, void* d_ws, size_t ws_size,
                              hipStream_t stream)
{
  (void)in_sizes; (void)n_in; (void)out_size; (void)ws_size;
  const float* feats   = (const float*)d_in[0];
  const int*   src     = (const int*)d_in[1];
  const int*   dst     = (const int*)d_in[2];
  const int*   n2g     = (const int*)d_in[3];
  const float* W_in    = (const float*)d_in[4];
  const float* b_in    = (const float*)d_in[5];
  const float* bng     = (const float*)d_in[6];
  const float* bnb     = (const float*)d_in[7];
  const float* bnm     = (const float*)d_in[8];
  const float* bnv     = (const float*)d_in[9];
  const float* gw_ih   = (const float*)d_in[10];
  const float* gw_hh   = (const float*)d_in[11];
  const float* gb_ih   = (const float*)d_in[12];
  const float* gb_hh   = (const float*)d_in[13];
  const float* w_aw    = (const float*)d_in[14];
  const float* b_aw    = (const float*)d_in[15];
  const float* lwih_f  = (const float*)d_in[16];
  const float* lwhh_f  = (const float*)d_in[17];
  const float* lbih_f  = (const float*)d_in[18];
  const float* lbhh_f  = (const float*)d_in[19];
  const float* lwih_b  = (const float*)d_in[20];
  const float* lwhh_b  = (const float*)d_in[21];
  const float* lbih_b  = (const float*)d_in[22];
  const float* lbhh_b  = (const float*)d_in[23];
  const float* W_out   = (const float*)d_in[24];
  const float* b_out   = (const float*)d_in[25];
  float* out = (float*)d_out;
  (void)lwhh_f;  // fwd w_hh unused: h0=0, only fwd step 0 needed

  float* ws = (float*)d_ws;
  size_t off = 0;
  auto alloc = [&](size_t n) { float* p = ws + off; off += (n + 63) & ~(size_t)63; return p; };
  float* h      = alloc((size_t)NP * 128);
  unsigned short* xhi   = (unsigned short*)alloc((size_t)NP * 64);
  unsigned short* agghi = (unsigned short*)alloc((size_t)NP * 64);
  unsigned short* Wp    = (unsigned short*)alloc(65536);
  float* bcat   = alloc(512);
  float* wnode  = alloc(NN);
  float* bnp    = alloc(NL * 256);
  unsigned short* xplh = (unsigned short*)alloc((size_t)NL * NG * 128);
  unsigned short* xpll = (unsigned short*)alloc((size_t)NL * NG * 128);
  unsigned short* Wihf = (unsigned short*)alloc(65536);
  unsigned short* Wihb = (unsigned short*)alloc(65536);
  unsigned short* Whhb = (unsigned short*)alloc(32768);
  float* bcf    = alloc(512);
  float* bcb    = alloc(512);
  float* gxb    = alloc((size_t)NL * NG * 512);
  float* gxf    = alloc((size_t)NG * 512);
  float* yf     = alloc((size_t)NG * 128);
  float* yb     = alloc((size_t)NG * 128);
  int* deg    = (int*)alloc(NN);
  int* rowptr = (int*)alloc(NN + 1);
  int* pos    = (int*)alloc(NN);
  int* colidx = (int*)alloc(NE);
  int* bsum   = (int*)alloc(256);
  int* boff   = (int*)alloc(256);

  // ---- one-time: CSR build + weight prepacks + BN prep ----
  hipMemsetAsync(deg, 0, (size_t)NN * sizeof(int), stream);
  k_hist<<<(NE + 255) / 256, 256, 0, stream>>>(dst, deg);
  k_scan1<<<196, 256, 0, stream>>>(deg, bsum);
  k_scan2<<<1, 256, 0, stream>>>(bsum, boff, rowptr);
  k_scan3<<<196, 256, 0, stream>>>(deg, boff, rowptr);
  hipMemcpyAsync(pos, rowptr, (size_t)NN * sizeof(int), hipMemcpyDeviceToDevice, stream);
  k_fill<<<(NE + 255) / 256, 256, 0, stream>>>(src, dst, pos, colidx);
  k_wpack<<<512, 256, 0, stream>>>(gw_ih, gw_hh, gb_ih, gb_hh, Wp, bcat);
  k_wpack_lstm<<<1280, 256, 0, stream>>>(lwih_f, lwih_b, lwhh_b, lbih_f, lbhh_f, lbih_b, lbhh_b,
                                         Wihf, Wihb, Whhb, bcf, bcb);
  k_bnprep_all<<<NL, 128, 0, stream>>>(bng, bnb, bnm, bnv, bnp);

  k_input_proj<<<1024, 256, 0, stream>>>(feats, W_in, b_in, h);

  for (int l = 0; l < NL; ++l) {
    const float* bnpl = bnp + l * 256;
    k_prep<<<3125, 256, 0, stream>>>(h, bnpl, w_aw, b_aw, xhi, wnode);
    k_gather<<<NN / 4, 256, 0, stream>>>(xhi, rowptr, colidx, agghi);
    k_readout<<<NG, 256, 0, stream>>>(h, wnode, n2g, xplh, xpll, l);
    k_gru_mfma<<<GRUGRID, 512, 0, stream>>>(h, xhi, agghi, Wp, bcat, bnpl);
  }

  // ---- LSTM: x-gates then recurrence ----
  k_xgates<<<96, 512, 0, stream>>>(xplh, xpll, Wihb, Wihf, bcb, bcf, gxb, gxf);
  k_lstm0<<<512, 256, 0, stream>>>(gxf, yf);
  k_lstm_rec<<<32, 512, 0, stream>>>(gxb, Whhb, yb);

  k_final<<<NG / 4, 256, 0, stream>>>(yf, yb, W_out, b_out, out);
}